// Round 12
// baseline (258.453 us; speedup 1.0000x reference)
//
#include <hip/hip_runtime.h>
#include <hip/hip_cooperative_groups.h>

namespace cg = cooperative_groups;

#define N_NODES 50000
#define N_EDGES 800000
#define IN_DIM 16
#define OUT_DIM 16
#define N_RELS 90
#define N_BASES 30

#define CAP 24            // bucket rows per node
#define LDS_STRIDE 260    // 256 + 4 pad floats per relation row
#define NBLK 256          // 1 block/CU -> cooperative co-residency guaranteed
#define EDGES_PER_BLK 3125  // 256 x 3125 = 800000, contiguous he stream

__device__ __forceinline__ float4 shfl_xor4(float4 v, int m) {
    float4 r;
    r.x = __shfl_xor(v.x, m); r.y = __shfl_xor(v.y, m);
    r.z = __shfl_xor(v.z, m); r.w = __shfl_xor(v.w, m);
    return r;
}

// ---------------------------------------------------------------------------
// ONE cooperative kernel: setup -> grid.sync -> compute -> grid.sync -> reduce
// ---------------------------------------------------------------------------
__global__ __launch_bounds__(1024) void fused_kernel(
    const float* __restrict__ h,
    const float* __restrict__ he,
    const int* __restrict__ src,
    const int* __restrict__ dst,
    const int* __restrict__ rel,
    const float* __restrict__ Ws,
    const float* __restrict__ Wa,
    const float* __restrict__ weight,
    const float* __restrict__ w_comp,
    float* __restrict__ WrelG,     // [90*256] staging
    float2* __restrict__ s13,      // [N_NODES]
    int* __restrict__ cnt,         // [N_NODES]
    float* __restrict__ bucket,    // [N_NODES*CAP*16]
    float* __restrict__ hout)      // [N_NODES*16]
{
    extern __shared__ float lw[];               // 90*260 floats = 93600 B
    __shared__ __align__(16) float la[48];      // folded attention vectors

    const int t = threadIdx.x;
    const int bid = blockIdx.x;

    // ================= Phase A: sliced setup =================
    if (t < 48) {
        int k = t / IN_DIM, i = t % IN_DIM;
        float acc = 0.f;
        #pragma unroll
        for (int o = 0; o < OUT_DIM; ++o)
            acc += Wa[k * OUT_DIM + o] * Ws[o * IN_DIM + i];
        la[t] = acc;
    }
    // Wrel -> global, 90 elems per block
    if (t < 90) {
        int f = bid * 90 + t;
        if (f < N_RELS * IN_DIM * OUT_DIM) {
            int a   = f / (N_RELS * OUT_DIM);
            int rem = f % (N_RELS * OUT_DIM);
            int r   = rem / OUT_DIM;
            int o   = rem % OUT_DIM;
            float acc = 0.f;
            #pragma unroll
            for (int bb = 0; bb < N_BASES; ++bb)
                acc += w_comp[r * N_BASES + bb] * weight[a * (N_BASES * OUT_DIM) + bb * OUT_DIM + o];
            WrelG[f] = acc;
        }
    }
    __syncthreads();   // la ready
    // s13 + cnt-zero (196 nodes/block) and hout-zero (196 float4/block)
    if (t < 196) {
        int n = bid * 196 + t;
        if (n < N_NODES) {
            const float4* p = (const float4*)(h + (size_t)n * IN_DIM);
            float d1 = 0.f, d3 = 0.f;
            #pragma unroll
            for (int i = 0; i < 4; ++i) {
                float4 v = p[i];
                d1 += v.x * la[4*i+0] + v.y * la[4*i+1] + v.z * la[4*i+2] + v.w * la[4*i+3];
                d3 += v.x * la[32+4*i+0] + v.y * la[32+4*i+1] + v.z * la[32+4*i+2] + v.w * la[32+4*i+3];
            }
            s13[n] = make_float2(d1, d3);
            cnt[n] = 0;
        }
        int idx = bid * 196 + t;
        if (idx < N_NODES * OUT_DIM / 4) {
            float4 z = {0.f, 0.f, 0.f, 0.f};
            ((float4*)hout)[idx] = z;
        }
    }

    cg::this_grid().sync();

    // ================= Phase B: edge compute (R10 body) =================
    // stage Wrel -> LDS (padded stride)
    for (int j = t; j < N_RELS * 64; j += 1024) {
        int r = j >> 6;
        int w = j & 63;
        float4 v = ((const float4*)WrelG)[r * 64 + w];
        *(float4*)(lw + r * LDS_STRIDE + w * 4) = v;
    }
    __syncthreads();

    {
        const int q = t & 3;
        const int grp = t >> 2;
        const int lbase = (t & 63) & ~3;
        const int ebeg = bid * EDGES_PER_BLK;
        const int eend = ebeg + EDGES_PER_BLK;

        float4 av = *(const float4*)(la + 16 + 4 * q);

        for (int base = ebeg + grp; base < eend; base += 1024) {
            int e[4], s[4], d[4], r[4];
            bool val[4];

            #pragma unroll
            for (int k = 0; k < 4; ++k) {
                e[k] = base + k * 256;
                val[k] = (e[k] < eend);
                int ec = val[k] ? e[k] : ebeg;
                s[k] = src[ec]; d[k] = dst[ec]; r[k] = rel[ec];
            }

            float4 heq[4], hq[4];
            float2 svs[4], svd[4];
            #pragma unroll
            for (int k = 0; k < 4; ++k) {
                int ec = val[k] ? e[k] : ebeg;
                heq[k] = *(const float4*)(he + (size_t)ec * IN_DIM + q * 4);
                hq[k]  = *(const float4*)(h  + (size_t)s[k] * IN_DIM + q * 4);
                svs[k] = s13[s[k]];
                svd[k] = s13[d[k]];
            }

            int slot[4];
            #pragma unroll
            for (int k = 0; k < 4; ++k) {
                slot[k] = 0;
                if (q == 0 && val[k]) slot[k] = atomicAdd(&cnt[d[k]], 1);
            }

            #pragma unroll
            for (int k = 0; k < 4; ++k) {
                if (!val[k]) continue;
                int sl = __shfl(slot[k], lbase);

                float pd = heq[k].x * av.x + heq[k].y * av.y + heq[k].z * av.z + heq[k].w * av.w;
                pd += __shfl_xor(pd, 1);
                pd += __shfl_xor(pd, 2);
                float score = svs[k].x + svd[k].y + pd;

                float4 o1 = shfl_xor4(hq[k], 1);
                float4 o2 = shfl_xor4(hq[k], 2);
                float4 o3 = shfl_xor4(o1, 2);
                bool q0 = (q == 0), q1 = (q == 1), q2 = (q == 2);
                float4 row0 = q0 ? hq[k] : q1 ? o1 : q2 ? o2 : o3;
                float4 row1 = q0 ? o1 : q1 ? hq[k] : q2 ? o3 : o2;
                float4 row2 = q0 ? o2 : q1 ? o3 : q2 ? hq[k] : o1;
                float4 row3 = q0 ? o3 : q1 ? o2 : q2 ? o1 : hq[k];
                float hs[16] = {row0.x,row0.y,row0.z,row0.w, row1.x,row1.y,row1.z,row1.w,
                                row2.x,row2.y,row2.z,row2.w, row3.x,row3.y,row3.z,row3.w};

                const float* wb = lw + (size_t)r[k] * LDS_STRIDE + q * 4;
                float4 acc = {0.f, 0.f, 0.f, 0.f};
                #pragma unroll
                for (int i = 0; i < 16; ++i) {
                    float4 w = *(const float4*)(wb + i * 16);
                    float hv = hs[i];
                    acc.x += hv * w.x; acc.y += hv * w.y; acc.z += hv * w.z; acc.w += hv * w.w;
                }
                acc.x *= score; acc.y *= score; acc.z *= score; acc.w *= score;

                if (sl < CAP) {
                    *(float4*)(bucket + ((size_t)d[k] * CAP + sl) * OUT_DIM + q * 4) = acc;
                } else {
                    float* outp = hout + (size_t)d[k] * OUT_DIM + q * 4;
                    atomicAdd(outp + 0, acc.x);
                    atomicAdd(outp + 1, acc.y);
                    atomicAdd(outp + 2, acc.z);
                    atomicAdd(outp + 3, acc.w);
                }
            }
        }
    }

    cg::this_grid().sync();

    // ================= Phase C: reduce =================
    {
        const int q = t & 3;
        const int p = (t >> 2) & 3;
        for (int idx = bid * 1024 + t; idx < N_NODES * 16; idx += NBLK * 1024) {
            int n = idx >> 4;
            int deg = cnt[n];
            int m = deg > CAP ? CAP : deg;
            const float4* bp = (const float4*)(bucket + (size_t)n * CAP * OUT_DIM) + q;
            float4 acc = {0.f, 0.f, 0.f, 0.f};
            for (int j = p; j < m; j += 4) {
                float4 v = bp[j * 4];
                acc.x += v.x; acc.y += v.y; acc.z += v.z; acc.w += v.w;
            }
            acc.x += __shfl_xor(acc.x, 4); acc.y += __shfl_xor(acc.y, 4);
            acc.z += __shfl_xor(acc.z, 4); acc.w += __shfl_xor(acc.w, 4);
            acc.x += __shfl_xor(acc.x, 8); acc.y += __shfl_xor(acc.y, 8);
            acc.z += __shfl_xor(acc.z, 8); acc.w += __shfl_xor(acc.w, 8);

            if (p == 0) {
                if (deg <= CAP) {
                    *(float4*)(hout + (size_t)n * OUT_DIM + q * 4) = acc;
                } else {
                    float* outp = hout + (size_t)n * OUT_DIM + q * 4;
                    atomicAdd(outp + 0, acc.x);
                    atomicAdd(outp + 1, acc.y);
                    atomicAdd(outp + 2, acc.z);
                    atomicAdd(outp + 3, acc.w);
                }
            }
        }
    }
}

// ===========================================================================
// Fallback (ws too small): prep + direct atomic scatter (known-correct).
// ===========================================================================
__global__ __launch_bounds__(256) void prep_kernel(
    const float* __restrict__ Ws, const float* __restrict__ Wa,
    const float* __restrict__ weight, const float* __restrict__ w_comp,
    float* __restrict__ Wrel, float* __restrict__ avec)
{
    int f = blockIdx.x * blockDim.x + threadIdx.x;
    if (f < N_RELS * IN_DIM * OUT_DIM) {
        int a   = f / (N_RELS * OUT_DIM);
        int rem = f % (N_RELS * OUT_DIM);
        int r   = rem / OUT_DIM;
        int o   = rem % OUT_DIM;
        float acc = 0.f;
        #pragma unroll
        for (int b = 0; b < N_BASES; ++b)
            acc += w_comp[r * N_BASES + b] * weight[a * (N_BASES * OUT_DIM) + b * OUT_DIM + o];
        Wrel[f] = acc;
    } else if (f < N_RELS * IN_DIM * OUT_DIM + 48) {
        int g = f - N_RELS * IN_DIM * OUT_DIM;
        int k = g / IN_DIM;
        int i = g % IN_DIM;
        float acc = 0.f;
        #pragma unroll
        for (int o = 0; o < OUT_DIM; ++o)
            acc += Wa[k * OUT_DIM + o] * Ws[o * IN_DIM + i];
        avec[g] = acc;
    }
}

__global__ __launch_bounds__(256) void edge_atomic_kernel(
    const float* __restrict__ h,
    const float* __restrict__ he,
    const int* __restrict__ src,
    const int* __restrict__ dst,
    const int* __restrict__ rel,
    const float* __restrict__ Wrel,
    const float* __restrict__ avec,
    float* __restrict__ hout)
{
    int e = blockIdx.x * blockDim.x + threadIdx.x;
    if (e >= N_EDGES) return;
    int s = src[e], d = dst[e], r = rel[e];
    float hs[IN_DIM];
    const float4* p = (const float4*)(h + (size_t)s * IN_DIM);
    #pragma unroll
    for (int i = 0; i < 4; ++i) {
        float4 v = p[i];
        hs[4*i+0] = v.x; hs[4*i+1] = v.y; hs[4*i+2] = v.z; hs[4*i+3] = v.w;
    }
    float score = 0.f;
    #pragma unroll
    for (int i = 0; i < IN_DIM; ++i) score += hs[i] * avec[i];
    const float4* qe = (const float4*)(he + (size_t)e * IN_DIM);
    #pragma unroll
    for (int i = 0; i < 4; ++i) {
        float4 v = qe[i];
        score += v.x * avec[16+4*i] + v.y * avec[17+4*i] + v.z * avec[18+4*i] + v.w * avec[19+4*i];
    }
    const float4* pd = (const float4*)(h + (size_t)d * IN_DIM);
    #pragma unroll
    for (int i = 0; i < 4; ++i) {
        float4 v = pd[i];
        score += v.x * avec[32+4*i] + v.y * avec[33+4*i] + v.z * avec[34+4*i] + v.w * avec[35+4*i];
    }
    float acc[OUT_DIM];
    #pragma unroll
    for (int o = 0; o < OUT_DIM; ++o) acc[o] = 0.f;
    const float* W = Wrel + (size_t)r * 256;
    #pragma unroll
    for (int i = 0; i < IN_DIM; ++i) {
        float hv = hs[i];
        #pragma unroll
        for (int o = 0; o < OUT_DIM; ++o) acc[o] += hv * W[i * OUT_DIM + o];
    }
    float* outp = hout + (size_t)d * OUT_DIM;
    #pragma unroll
    for (int o = 0; o < OUT_DIM; ++o) atomicAdd(outp + o, acc[o] * score);
}

extern "C" void kernel_launch(void* const* d_in, const int* in_sizes, int n_in,
                              void* d_out, int out_size, void* d_ws, size_t ws_size,
                              hipStream_t stream) {
    const float* h      = (const float*)d_in[0];
    const float* he     = (const float*)d_in[1];
    const float* Ws     = (const float*)d_in[2];
    const float* Wa     = (const float*)d_in[3];
    const float* weight = (const float*)d_in[4];
    const float* w_comp = (const float*)d_in[5];
    const int*   src    = (const int*)d_in[6];
    const int*   dst    = (const int*)d_in[7];
    const int*   rel    = (const int*)d_in[8];
    float* hout = (float*)d_out;

    // ws layout (float offsets)
    const size_t OFF_WREL   = 0;         // 23040 f
    const size_t OFF_S13    = 23040;     // 100000 f
    const size_t OFF_CNT    = 123040;    // 50000 i
    const size_t OFF_BUCKET = 173040;    // N*CAP*16 f (16-f aligned)
    const size_t NEED_BUCKET = (OFF_BUCKET + (size_t)N_NODES * CAP * OUT_DIM) * 4;

    float* wsf   = (float*)d_ws;
    float* WrelG = wsf + OFF_WREL;
    float2* s13  = (float2*)(wsf + OFF_S13);
    int* cnt     = (int*)(wsf + OFF_CNT);

    if (ws_size >= NEED_BUCKET) {
        float* bucket = wsf + OFF_BUCKET;

        void* args[] = {
            (void*)&h, (void*)&he, (void*)&src, (void*)&dst, (void*)&rel,
            (void*)&Ws, (void*)&Wa, (void*)&weight, (void*)&w_comp,
            (void*)&WrelG, (void*)&s13, (void*)&cnt, (void*)&bucket, (void*)&hout
        };
        hipLaunchCooperativeKernel((void*)fused_kernel, dim3(NBLK), dim3(1024),
                                   args, N_RELS * LDS_STRIDE * sizeof(float), stream);
    } else {
        hipMemsetAsync(d_out, 0, (size_t)out_size * sizeof(float), stream);
        float* Wrel = wsf;
        float* avf  = wsf + 23040;
        int total = N_RELS * IN_DIM * OUT_DIM + 48;
        prep_kernel<<<(total + 255) / 256, 256, 0, stream>>>(Ws, Wa, weight, w_comp, Wrel, avf);
        edge_atomic_kernel<<<(N_EDGES + 255) / 256, 256, 0, stream>>>(
            h, he, src, dst, rel, Wrel, avf, hout);
    }
}

// Round 13
// 233.177 us; speedup vs baseline: 1.1084x; 1.1084x over previous
//
#include <hip/hip_runtime.h>

#define N_NODES 50000
#define N_EDGES 800000
#define IN_DIM 16
#define OUT_DIM 16
#define N_RELS 90
#define N_BASES 30

#define CAP 24            // bucket rows per node (avg deg 16)
#define LDS_STRIDE 260    // 256 + 4 pad floats per relation row
#define EDGES_PER_BLK 3125  // 256 blocks x 3125 = 800000, contiguous he stream
#define BATCH 8

#define PREP_BLOCKS 91   // 91*256 = 23296 >= 23088
#define DOTS_BLOCKS 196  // 196*256 = 50176 >= 50000
#define ZERO_BLOCKS 196
#define HZ_BLOCKS 782    // 782*256 float4 >= 200000 float4 (zero hout)

__device__ __forceinline__ float4 shfl_xor4(float4 v, int m) {
    float4 r;
    r.x = __shfl_xor(v.x, m); r.y = __shfl_xor(v.y, m);
    r.z = __shfl_xor(v.z, m); r.w = __shfl_xor(v.w, m);
    return r;
}

// ---------------------------------------------------------------------------
// Setup: [0,91) prep Wrel+avec; [91,287) node dots; [287,483) zero cnt;
// [483,1265) zero hout.
// ---------------------------------------------------------------------------
__global__ __launch_bounds__(256) void setup_kernel(
    const float* __restrict__ Ws,
    const float* __restrict__ Wa,
    const float* __restrict__ weight,
    const float* __restrict__ w_comp,
    const float* __restrict__ h,
    float* __restrict__ Wrel,
    float* __restrict__ avec,
    float2* __restrict__ s13,
    int* __restrict__ cnt,
    float* __restrict__ hout)
{
    int b = blockIdx.x;
    if (b < PREP_BLOCKS) {
        int f = b * 256 + threadIdx.x;
        if (f < N_RELS * IN_DIM * OUT_DIM) {
            int a   = f / (N_RELS * OUT_DIM);
            int rem = f % (N_RELS * OUT_DIM);
            int r   = rem / OUT_DIM;
            int o   = rem % OUT_DIM;
            float acc = 0.f;
            #pragma unroll
            for (int bb = 0; bb < N_BASES; ++bb)
                acc += w_comp[r * N_BASES + bb] * weight[a * (N_BASES * OUT_DIM) + bb * OUT_DIM + o];
            Wrel[f] = acc;
        } else if (f < N_RELS * IN_DIM * OUT_DIM + 48) {
            int g = f - N_RELS * IN_DIM * OUT_DIM;
            int k = g / IN_DIM;
            int i = g % IN_DIM;
            float acc = 0.f;
            #pragma unroll
            for (int o = 0; o < OUT_DIM; ++o)
                acc += Wa[k * OUT_DIM + o] * Ws[o * IN_DIM + i];
            avec[g] = acc;
        }
    } else if (b < PREP_BLOCKS + DOTS_BLOCKS) {
        __shared__ float la[48];
        if (threadIdx.x < 48) {
            int k = threadIdx.x / IN_DIM;
            int i = threadIdx.x % IN_DIM;
            float acc = 0.f;
            #pragma unroll
            for (int o = 0; o < OUT_DIM; ++o)
                acc += Wa[k * OUT_DIM + o] * Ws[o * IN_DIM + i];
            la[threadIdx.x] = acc;
        }
        __syncthreads();
        int n = (b - PREP_BLOCKS) * 256 + threadIdx.x;
        if (n >= N_NODES) return;
        const float4* p = (const float4*)(h + (size_t)n * IN_DIM);
        float d1 = 0.f, d3 = 0.f;
        #pragma unroll
        for (int i = 0; i < 4; ++i) {
            float4 v = p[i];
            d1 += v.x * la[4*i+0] + v.y * la[4*i+1] + v.z * la[4*i+2] + v.w * la[4*i+3];
            d3 += v.x * la[32+4*i+0] + v.y * la[32+4*i+1] + v.z * la[32+4*i+2] + v.w * la[32+4*i+3];
        }
        s13[n] = make_float2(d1, d3);
    } else if (b < PREP_BLOCKS + DOTS_BLOCKS + ZERO_BLOCKS) {
        int n = (b - PREP_BLOCKS - DOTS_BLOCKS) * 256 + threadIdx.x;
        if (n < N_NODES) cnt[n] = 0;
    } else {
        int idx = (b - PREP_BLOCKS - DOTS_BLOCKS - ZERO_BLOCKS) * 256 + threadIdx.x;
        if (idx < N_NODES * OUT_DIM / 4) {
            float4 z = {0.f, 0.f, 0.f, 0.f};
            ((float4*)hout)[idx] = z;
        }
    }
}

// ---------------------------------------------------------------------------
// Edge compute: f32 Wrel in LDS (93.6KB, 1 block/CU), 1024 threads,
// __launch_bounds__(1024, 4): 4 waves/EU declared -> 512-VGPR budget so the
// 8-edge batch's operands actually stay in registers (R10's 64-VGPR ceiling
// was the MLP limiter). Loads-then-process, 4 lanes/edge.
// ---------------------------------------------------------------------------
__global__ __launch_bounds__(1024, 4) void compute_lds_kernel(
    const float* __restrict__ h,
    const float* __restrict__ he,
    const int* __restrict__ src,
    const int* __restrict__ dst,
    const int* __restrict__ rel,
    const float* __restrict__ Wrel,
    const float* __restrict__ avec,
    const float2* __restrict__ s13,
    int* __restrict__ cnt,
    float* __restrict__ bucket,   // [N_NODES*CAP*16]
    float* __restrict__ hout)     // overflow target (pre-zeroed)
{
    extern __shared__ float lw[];   // [N_RELS * LDS_STRIDE]

    for (int j = threadIdx.x; j < N_RELS * 64; j += 1024) {
        int r = j >> 6;
        int w = j & 63;
        float4 v = ((const float4*)Wrel)[r * 64 + w];
        *(float4*)(lw + r * LDS_STRIDE + w * 4) = v;
    }
    __syncthreads();

    const int t = threadIdx.x;
    const int q = t & 3;
    const int grp = t >> 2;                 // 0..255
    const int lbase = (t & 63) & ~3;
    const int ebeg = blockIdx.x * EDGES_PER_BLK;
    const int eend = ebeg + EDGES_PER_BLK;

    float4 av = *(const float4*)(avec + 16 + 4 * q);

    for (int base = ebeg + grp; base < eend; base += 256 * BATCH) {
        int e[BATCH], s[BATCH], d[BATCH], r[BATCH];
        bool val[BATCH];

        // ---- [1] all idx loads (independent chains) ----
        #pragma unroll
        for (int k = 0; k < BATCH; ++k) {
            e[k] = base + k * 256;
            val[k] = (e[k] < eend);
            int ec = val[k] ? e[k] : ebeg;
            s[k] = src[ec]; d[k] = dst[ec]; r[k] = rel[ec];
        }

        // ---- [2] all data loads (independent gather chains) ----
        float4 heq[BATCH], hq[BATCH];
        float2 svs[BATCH], svd[BATCH];
        #pragma unroll
        for (int k = 0; k < BATCH; ++k) {
            int ec = val[k] ? e[k] : ebeg;
            heq[k] = *(const float4*)(he + (size_t)ec * IN_DIM + q * 4);
            hq[k]  = *(const float4*)(h  + (size_t)s[k] * IN_DIM + q * 4);
            svs[k] = s13[s[k]];
            svd[k] = s13[d[k]];
        }

        // ---- [3] all slot atomics ----
        int slot[BATCH];
        #pragma unroll
        for (int k = 0; k < BATCH; ++k) {
            slot[k] = 0;
            if (q == 0 && val[k]) slot[k] = atomicAdd(&cnt[d[k]], 1);
        }

        // ---- [4] process ----
        #pragma unroll
        for (int k = 0; k < BATCH; ++k) {
            if (!val[k]) continue;   // uniform across the 4-lane group
            int sl = __shfl(slot[k], lbase);

            float pd = heq[k].x * av.x + heq[k].y * av.y + heq[k].z * av.z + heq[k].w * av.w;
            pd += __shfl_xor(pd, 1);
            pd += __shfl_xor(pd, 2);
            float score = svs[k].x + svd[k].y + pd;

            float4 o1 = shfl_xor4(hq[k], 1);
            float4 o2 = shfl_xor4(hq[k], 2);
            float4 o3 = shfl_xor4(o1, 2);
            bool q0 = (q == 0), q1 = (q == 1), q2 = (q == 2);
            float4 row0 = q0 ? hq[k] : q1 ? o1 : q2 ? o2 : o3;
            float4 row1 = q0 ? o1 : q1 ? hq[k] : q2 ? o3 : o2;
            float4 row2 = q0 ? o2 : q1 ? o3 : q2 ? hq[k] : o1;
            float4 row3 = q0 ? o3 : q1 ? o2 : q2 ? o1 : hq[k];
            float hs[16] = {row0.x,row0.y,row0.z,row0.w, row1.x,row1.y,row1.z,row1.w,
                            row2.x,row2.y,row2.z,row2.w, row3.x,row3.y,row3.z,row3.w};

            const float* wb = lw + (size_t)r[k] * LDS_STRIDE + q * 4;
            float4 acc = {0.f, 0.f, 0.f, 0.f};
            #pragma unroll
            for (int i = 0; i < 16; ++i) {
                float4 w = *(const float4*)(wb + i * 16);
                float hv = hs[i];
                acc.x += hv * w.x; acc.y += hv * w.y; acc.z += hv * w.z; acc.w += hv * w.w;
            }
            acc.x *= score; acc.y *= score; acc.z *= score; acc.w *= score;

            if (sl < CAP) {
                *(float4*)(bucket + ((size_t)d[k] * CAP + sl) * OUT_DIM + q * 4) = acc;
            } else {
                float* outp = hout + (size_t)d[k] * OUT_DIM + q * 4;
                atomicAdd(outp + 0, acc.x);
                atomicAdd(outp + 1, acc.y);
                atomicAdd(outp + 2, acc.z);
                atomicAdd(outp + 3, acc.w);
            }
        }
    }
}

// ---------------------------------------------------------------------------
// Reduce: 16 lanes/node (quarter q x 4 j-streams), 2-step butterfly; plain
// store for deg<=CAP, atomicAdd for deg>CAP (overflow already in hout).
// ---------------------------------------------------------------------------
__global__ __launch_bounds__(256) void reduce_bucket_kernel(
    const float* __restrict__ bucket,
    const int* __restrict__ cnt,
    float* __restrict__ hout)
{
    int tid = blockIdx.x * 256 + threadIdx.x;
    int n = tid >> 4;
    int l = tid & 15;
    int q = l & 3;
    int p = l >> 2;
    if (n >= N_NODES) return;

    int deg = cnt[n];
    int m = deg > CAP ? CAP : deg;
    const float4* bp = (const float4*)(bucket + (size_t)n * CAP * OUT_DIM) + q;
    float4 acc = {0.f, 0.f, 0.f, 0.f};
    for (int j = p; j < m; j += 4) {
        float4 v = bp[j * 4];
        acc.x += v.x; acc.y += v.y; acc.z += v.z; acc.w += v.w;
    }
    acc.x += __shfl_xor(acc.x, 4); acc.y += __shfl_xor(acc.y, 4);
    acc.z += __shfl_xor(acc.z, 4); acc.w += __shfl_xor(acc.w, 4);
    acc.x += __shfl_xor(acc.x, 8); acc.y += __shfl_xor(acc.y, 8);
    acc.z += __shfl_xor(acc.z, 8); acc.w += __shfl_xor(acc.w, 8);

    if (p == 0) {
        if (deg <= CAP) {
            *(float4*)(hout + (size_t)n * OUT_DIM + q * 4) = acc;
        } else {
            float* outp = hout + (size_t)n * OUT_DIM + q * 4;
            atomicAdd(outp + 0, acc.x);
            atomicAdd(outp + 1, acc.y);
            atomicAdd(outp + 2, acc.z);
            atomicAdd(outp + 3, acc.w);
        }
    }
}

// ===========================================================================
// Fallback (ws too small): direct atomic scatter (known-correct).
// ===========================================================================
__global__ __launch_bounds__(256) void prep_kernel(
    const float* __restrict__ Ws, const float* __restrict__ Wa,
    const float* __restrict__ weight, const float* __restrict__ w_comp,
    float* __restrict__ Wrel, float* __restrict__ avec)
{
    int f = blockIdx.x * blockDim.x + threadIdx.x;
    if (f < N_RELS * IN_DIM * OUT_DIM) {
        int a   = f / (N_RELS * OUT_DIM);
        int rem = f % (N_RELS * OUT_DIM);
        int r   = rem / OUT_DIM;
        int o   = rem % OUT_DIM;
        float acc = 0.f;
        #pragma unroll
        for (int b = 0; b < N_BASES; ++b)
            acc += w_comp[r * N_BASES + b] * weight[a * (N_BASES * OUT_DIM) + b * OUT_DIM + o];
        Wrel[f] = acc;
    } else if (f < N_RELS * IN_DIM * OUT_DIM + 48) {
        int g = f - N_RELS * IN_DIM * OUT_DIM;
        int k = g / IN_DIM;
        int i = g % IN_DIM;
        float acc = 0.f;
        #pragma unroll
        for (int o = 0; o < OUT_DIM; ++o)
            acc += Wa[k * OUT_DIM + o] * Ws[o * IN_DIM + i];
        avec[g] = acc;
    }
}

__global__ __launch_bounds__(256) void edge_atomic_kernel(
    const float* __restrict__ h,
    const float* __restrict__ he,
    const int* __restrict__ src,
    const int* __restrict__ dst,
    const int* __restrict__ rel,
    const float* __restrict__ Wrel,
    const float* __restrict__ avec,
    float* __restrict__ hout)
{
    int e = blockIdx.x * blockDim.x + threadIdx.x;
    if (e >= N_EDGES) return;
    int s = src[e], d = dst[e], r = rel[e];
    float hs[IN_DIM];
    const float4* p = (const float4*)(h + (size_t)s * IN_DIM);
    #pragma unroll
    for (int i = 0; i < 4; ++i) {
        float4 v = p[i];
        hs[4*i+0] = v.x; hs[4*i+1] = v.y; hs[4*i+2] = v.z; hs[4*i+3] = v.w;
    }
    float score = 0.f;
    #pragma unroll
    for (int i = 0; i < IN_DIM; ++i) score += hs[i] * avec[i];
    const float4* qe = (const float4*)(he + (size_t)e * IN_DIM);
    #pragma unroll
    for (int i = 0; i < 4; ++i) {
        float4 v = qe[i];
        score += v.x * avec[16+4*i] + v.y * avec[17+4*i] + v.z * avec[18+4*i] + v.w * avec[19+4*i];
    }
    const float4* pd = (const float4*)(h + (size_t)d * IN_DIM);
    #pragma unroll
    for (int i = 0; i < 4; ++i) {
        float4 v = pd[i];
        score += v.x * avec[32+4*i] + v.y * avec[33+4*i] + v.z * avec[34+4*i] + v.w * avec[35+4*i];
    }
    float acc[OUT_DIM];
    #pragma unroll
    for (int o = 0; o < OUT_DIM; ++o) acc[o] = 0.f;
    const float* W = Wrel + (size_t)r * 256;
    #pragma unroll
    for (int i = 0; i < IN_DIM; ++i) {
        float hv = hs[i];
        #pragma unroll
        for (int o = 0; o < OUT_DIM; ++o) acc[o] += hv * W[i * OUT_DIM + o];
    }
    float* outp = hout + (size_t)d * OUT_DIM;
    #pragma unroll
    for (int o = 0; o < OUT_DIM; ++o) atomicAdd(outp + o, acc[o] * score);
}

extern "C" void kernel_launch(void* const* d_in, const int* in_sizes, int n_in,
                              void* d_out, int out_size, void* d_ws, size_t ws_size,
                              hipStream_t stream) {
    const float* h      = (const float*)d_in[0];
    const float* he     = (const float*)d_in[1];
    const float* Ws     = (const float*)d_in[2];
    const float* Wa     = (const float*)d_in[3];
    const float* weight = (const float*)d_in[4];
    const float* w_comp = (const float*)d_in[5];
    const int*   src    = (const int*)d_in[6];
    const int*   dst    = (const int*)d_in[7];
    const int*   rel    = (const int*)d_in[8];
    float* hout = (float*)d_out;

    // ws layout (float offsets)
    const size_t OFF_WREL   = 0;         // 23040 f
    const size_t OFF_AVEC   = 23040;     // 48 f (+16 pad)
    const size_t OFF_S13    = 23104;     // 100000 f
    const size_t OFF_CNT    = 123104;    // 50000 i
    const size_t OFF_BUCKET = 173104;    // N*CAP*16 f (16-f aligned)
    const size_t NEED_BUCKET = (OFF_BUCKET + (size_t)N_NODES * CAP * OUT_DIM) * 4;

    float* wsf  = (float*)d_ws;
    float* Wrel = wsf + OFF_WREL;
    float* avec = wsf + OFF_AVEC;
    float2* s13 = (float2*)(wsf + OFF_S13);
    int* cnt    = (int*)(wsf + OFF_CNT);

    if (ws_size >= NEED_BUCKET) {
        float* bucket = wsf + OFF_BUCKET;

        setup_kernel<<<PREP_BLOCKS + DOTS_BLOCKS + ZERO_BLOCKS + HZ_BLOCKS, 256, 0, stream>>>(
            Ws, Wa, weight, w_comp, h, Wrel, avec, s13, cnt, hout);
        compute_lds_kernel<<<N_EDGES / EDGES_PER_BLK, 1024,
                             N_RELS * LDS_STRIDE * sizeof(float), stream>>>(
            h, he, src, dst, rel, Wrel, avec, s13, cnt, bucket, hout);
        reduce_bucket_kernel<<<(N_NODES * 16 + 255) / 256, 256, 0, stream>>>(
            bucket, cnt, hout);
    } else {
        hipMemsetAsync(d_out, 0, (size_t)out_size * sizeof(float), stream);
        int total = N_RELS * IN_DIM * OUT_DIM + 48;
        prep_kernel<<<(total + 255) / 256, 256, 0, stream>>>(Ws, Wa, weight, w_comp, Wrel, avec);
        edge_atomic_kernel<<<(N_EDGES + 255) / 256, 256, 0, stream>>>(
            h, he, src, dst, rel, Wrel, avec, hout);
    }
}